// Round 4
// baseline (825.289 us; speedup 1.0000x reference)
//
#include <hip/hip_runtime.h>

// HeteroSAGE on MI355X — round 4: LDS-staged MFMA GEMM (m97-style).
// R3 post-mortem: mfma_gemm was latency-bound (MfmaUtil 2.4%, VALUBusy 15%,
// HBM 14%) because A-fragments were loaded straight from global with the MFMA
// lane layout (64 lanes -> 64 strided cache lines per load) and the epilogue
// did 128 scalar 2B gathers + 128 scalar 2B stores per thread.
// Fix: coalesced global->LDS staging for A, LDS round-trip for the epilogue
// (coalesced read-out, 16B/lane P-gathers, 8B/lane stores).

#define N_TX    200000
#define N_CARD  50000
#define N_MERCH 10000
#define NE      200000

typedef __attribute__((ext_vector_type(8))) short short8;
typedef __attribute__((ext_vector_type(4))) short short4v;
typedef __attribute__((ext_vector_type(4))) float f32x4;

__device__ inline unsigned short f2b(float f) {
    unsigned u = __builtin_bit_cast(unsigned, f);
    unsigned r = (u + 0x7fffu + ((u >> 16) & 1u)) >> 16;   // RNE
    return (unsigned short)r;
}
__device__ inline float b2f(unsigned short s) {
    return __builtin_bit_cast(float, (unsigned)s << 16);
}

// ---------------------------------------------------------------------------
// OUT[M,128] = act( A1[rowIdx1] @ W1 (+ A2 @ W2) + bias + P1[I1[r]] + P2[I2[r]] )
// optional head: out[r] = relu(row) . h2W + h2b  (fp32 out)
// WT* = bf16 weights transposed to [N=128][K]. A1 fp32 (a1_f32) or bf16.
// Block: 128 rows x 128 cols, 4 waves (wave = 2 m-tiles x 8 n-tiles 16x16x32).
__global__ __launch_bounds__(256, 2) void mfma_gemm(
    const void* __restrict__ A1, int a1_f32, const int* __restrict__ rowIdx1,
    int K1, const unsigned short* __restrict__ WT1,
    const void* __restrict__ A2, int K2, const unsigned short* __restrict__ WT2,
    const float* __restrict__ bias,
    const unsigned short* __restrict__ P1, const int* __restrict__ I1,
    const unsigned short* __restrict__ P2, const int* __restrict__ I2,
    int do_relu, const float* __restrict__ h2W, const float* __restrict__ h2b,
    void* __restrict__ OUT, int M)
{
    __shared__ __align__(16) char smem[2 * 128 * 136 * 2];   // 69632 B
    unsigned short* As = (unsigned short*)smem;               // [128][K+8]
    unsigned short* Ws = (unsigned short*)(smem + 128 * 136 * 2);
    float* Os = (float*)smem;                                 // [128][132] (union)

    const int tid  = threadIdx.x;
    const int wave = tid >> 6;
    const int lane = tid & 63;
    const int quad = lane >> 4;
    const int l15  = lane & 15;
    const int base = blockIdx.x * 128;

    f32x4 acc[2][8];
#pragma unroll
    for (int mt = 0; mt < 2; ++mt)
#pragma unroll
        for (int nt = 0; nt < 8; ++nt)
            acc[mt][nt] = (f32x4){0.f, 0.f, 0.f, 0.f};

    for (int pass = 0; pass < 2; ++pass) {
        const void* A = (pass == 0) ? A1 : A2;
        if (!A) break;
        const int K = (pass == 0) ? K1 : K2;
        const unsigned short* WTg = (pass == 0) ? WT1 : WT2;
        const int* rIdx = (pass == 0) ? rowIdx1 : nullptr;
        const int a_f32 = (pass == 0) ? a1_f32 : 0;
        const int stride = K + 8;
        const int nkk = K >> 5;                // 2 (K=64) or 4 (K=128)
        const int klog = (K == 128) ? 7 : 6;
        const int kmask = K - 1;

        __syncthreads();   // protect previous pass/phase LDS reads

        // ---- stage A tile (128 rows x K) into LDS, coalesced ----
        if (a_f32) {
            const float* Af = (const float*)A;
            const int iters = (K == 128) ? 16 : 8;
            for (int it = 0; it < iters; ++it) {
                int u = tid * 4 + it * 1024;          // f32 element index
                int row = u >> klog;
                int col = u & kmask;
                int gr = base + row;
                int ar = (gr < M) ? (rIdx ? rIdx[gr] : gr) : 0;
                float4 v = *reinterpret_cast<const float4*>(Af + (size_t)ar * K + col);
                short4v t;
                t[0] = (short)f2b(v.x); t[1] = (short)f2b(v.y);
                t[2] = (short)f2b(v.z); t[3] = (short)f2b(v.w);
                *reinterpret_cast<short4v*>(&As[row * stride + col]) = t;
            }
        } else {
            const unsigned short* Ab = (const unsigned short*)A;
            const int iters = (K == 128) ? 8 : 4;
            for (int it = 0; it < iters; ++it) {
                int u = tid * 8 + it * 2048;          // bf16 element index
                int row = u >> klog;
                int col = u & kmask;
                int gr = base + row;
                int ar = (gr < M) ? (rIdx ? rIdx[gr] : gr) : 0;
                *reinterpret_cast<short8*>(&As[row * stride + col]) =
                    *reinterpret_cast<const short8*>(Ab + (size_t)ar * K + col);
            }
        }
        // ---- stage W tile (128 rows x K, row-major [n][k]) ----
        {
            const int iters = (K == 128) ? 8 : 4;
            for (int it = 0; it < iters; ++it) {
                int u = tid * 8 + it * 2048;
                int row = u >> klog;
                int col = u & kmask;
                *reinterpret_cast<short8*>(&Ws[row * stride + col]) =
                    *reinterpret_cast<const short8*>(WTg + u);
            }
        }
        __syncthreads();

        // ---- fragments from LDS + MFMA ----
        short8 af[2][4];
#pragma unroll
        for (int mt = 0; mt < 2; ++mt) {
            const unsigned short* ap =
                &As[(wave * 32 + mt * 16 + l15) * stride + quad * 8];
#pragma unroll
            for (int kk = 0; kk < 4; ++kk) if (kk < nkk)
                af[mt][kk] = *reinterpret_cast<const short8*>(ap + kk * 32);
        }
#pragma unroll
        for (int nt = 0; nt < 8; ++nt) {
            short8 bf[4];
            const unsigned short* bp = &Ws[(nt * 16 + l15) * stride + quad * 8];
#pragma unroll
            for (int kk = 0; kk < 4; ++kk) if (kk < nkk)
                bf[kk] = *reinterpret_cast<const short8*>(bp + kk * 32);
#pragma unroll
            for (int mt = 0; mt < 2; ++mt)
#pragma unroll
                for (int kk = 0; kk < 4; ++kk) if (kk < nkk)
                    acc[mt][nt] = __builtin_amdgcn_mfma_f32_16x16x32_bf16(
                        af[mt][kk], bf[kk], acc[mt][nt], 0, 0, 0);
        }
    }

    // ---- epilogue phase 1: acc (+bias) -> LDS fp32 tile ----
    float bias_v[8];
#pragma unroll
    for (int nt = 0; nt < 8; ++nt)
        bias_v[nt] = bias ? bias[nt * 16 + l15] : 0.f;

    __syncthreads();   // done reading As/Ws; Os overlays them
#pragma unroll
    for (int mt = 0; mt < 2; ++mt) {
        int rbase = wave * 32 + mt * 16 + quad * 4;
#pragma unroll
        for (int reg = 0; reg < 4; ++reg)
#pragma unroll
            for (int nt = 0; nt < 8; ++nt)
                Os[(rbase + reg) * 132 + nt * 16 + l15] =
                    acc[mt][nt][reg] + bias_v[nt];
    }
    __syncthreads();

    // ---- epilogue phase 2: coalesced read-out, P-gather add, relu, store ----
    const int col4 = (tid & 31) * 4;
    float4 h2w4 = make_float4(0.f, 0.f, 0.f, 0.f);
    if (h2W) h2w4 = *reinterpret_cast<const float4*>(h2W + col4);
    unsigned short* OUTb = (unsigned short*)OUT;
    float* OUTf = (float*)OUT;

#pragma unroll
    for (int it = 0; it < 16; ++it) {
        int row = it * 8 + (tid >> 5);
        int gr = base + row;
        bool valid = gr < M;
        int grc = valid ? gr : 0;
        float4 o = *reinterpret_cast<const float4*>(&Os[row * 132 + col4]);
        if (P1) {
            size_t ix = (size_t)(I1 ? I1[grc] : grc) * 128 + col4;
            short4v p = *reinterpret_cast<const short4v*>(P1 + ix);
            o.x += b2f((unsigned short)p[0]); o.y += b2f((unsigned short)p[1]);
            o.z += b2f((unsigned short)p[2]); o.w += b2f((unsigned short)p[3]);
        }
        if (P2) {
            size_t ix = (size_t)(I2 ? I2[grc] : grc) * 128 + col4;
            short4v p = *reinterpret_cast<const short4v*>(P2 + ix);
            o.x += b2f((unsigned short)p[0]); o.y += b2f((unsigned short)p[1]);
            o.z += b2f((unsigned short)p[2]); o.w += b2f((unsigned short)p[3]);
        }
        if (do_relu) {
            o.x = fmaxf(o.x, 0.f); o.y = fmaxf(o.y, 0.f);
            o.z = fmaxf(o.z, 0.f); o.w = fmaxf(o.w, 0.f);
        }
        if (h2W) {
            float s = o.x * h2w4.x + o.y * h2w4.y + o.z * h2w4.z + o.w * h2w4.w;
            s += __shfl_xor(s, 1);  s += __shfl_xor(s, 2);
            s += __shfl_xor(s, 4);  s += __shfl_xor(s, 8);
            s += __shfl_xor(s, 16);
            if ((tid & 31) == 0 && valid) OUTf[gr] = s + h2b[0];
        } else if (valid) {
            short4v t;
            t[0] = (short)f2b(o.x); t[1] = (short)f2b(o.y);
            t[2] = (short)f2b(o.z); t[3] = (short)f2b(o.w);
            *reinterpret_cast<short4v*>(OUTb + (size_t)gr * 128 + col4) = t;
        }
    }
}

// ---------------------------------------------------------------------------
// Weight prep: fp32 [K][128] -> bf16 transposed [128][K]; job (6,13) also
// builds Wsum=Wr0+Wr2 and bsum=bl0+bl2. 18 jobs x 16384-short slots.
__global__ __launch_bounds__(256) void convert_weights(
    const float* __restrict__ tx_W, const float* __restrict__ card_proj_W,
    const float* __restrict__ merch_proj_W, const float* __restrict__ h1_W,
    const float* __restrict__ conv_Wl, const float* __restrict__ conv_Wr,
    const float* __restrict__ conv_bl,
    unsigned short* __restrict__ WT, float* __restrict__ bsum)
{
    int job = blockIdx.y;
    int K = 128;
    const float* src = nullptr;
    const float* src2 = nullptr;
    if (job == 0) src = tx_W;
    else if (job == 1) { src = card_proj_W; K = 64; }
    else if (job == 2) { src = merch_proj_W; K = 64; }
    else if (job == 3) src = h1_W;
    else {
        int l = (job - 4) / 7, e = (job - 4) % 7;
        const float* Wl = conv_Wl + (size_t)l * 4 * 16384;
        const float* Wr = conv_Wr + (size_t)l * 4 * 16384;
        switch (e) {
            case 0: src = Wl; break;
            case 1: src = Wl + 16384; break;
            case 2: src = Wl + 2 * 16384; break;
            case 3: src = Wl + 3 * 16384; break;
            case 4: src = Wr + 16384; break;
            case 5: src = Wr + 3 * 16384; break;
            default:
                src = Wr; src2 = Wr + 2 * 16384;
                if (blockIdx.x == 0 && threadIdx.x < 128) {
                    const float* bl = conv_bl + (size_t)l * 4 * 128;
                    bsum[l * 128 + threadIdx.x] =
                        bl[threadIdx.x] + bl[2 * 128 + threadIdx.x];
                }
                break;
        }
    }
    int e = blockIdx.x * 256 + threadIdx.x;
    if (e < (K << 7)) {
        int n = (K == 128) ? (e >> 7) : (e >> 6);
        int k = e & (K - 1);
        float v = src[(size_t)k * 128 + n];
        if (src2) v += src2[(size_t)k * 128 + n];
        WT[(size_t)job * 16384 + n * K + k] = f2b(v);
    }
}

// ---------------------------------------------------------------------------
// CSR build (edges fixed within call; reused across layers)
__global__ __launch_bounds__(256) void hist_kernel(
    const int* __restrict__ e_card, const int* __restrict__ e_merch,
    int* __restrict__ hist_c, int* __restrict__ hist_m, int E)
{
    int i = blockIdx.x * 256 + threadIdx.x;
    if (i < E) {
        atomicAdd(&hist_c[e_card[i]], 1);
        atomicAdd(&hist_m[e_merch[i]], 1);
    }
}

__global__ __launch_bounds__(1024) void scan2_kernel(
    const int* __restrict__ hist_c, int* __restrict__ offs_c, int* __restrict__ cur_c, int nc,
    const int* __restrict__ hist_m, int* __restrict__ offs_m, int* __restrict__ cur_m, int nm)
{
    const int* hist = (blockIdx.x == 0) ? hist_c : hist_m;
    int* offs = (blockIdx.x == 0) ? offs_c : offs_m;
    int* cursor = (blockIdx.x == 0) ? cur_c : cur_m;
    int n = (blockIdx.x == 0) ? nc : nm;
    __shared__ int wsum[16];
    __shared__ int s_carry;
    const int tid = threadIdx.x, lane = tid & 63, wid = tid >> 6;
    if (tid == 0) s_carry = 0;
    __syncthreads();
    for (int base = 0; base < n; base += 1024) {
        int i = base + tid;
        int v = (i < n) ? hist[i] : 0;
        int x = v;
#pragma unroll
        for (int d = 1; d < 64; d <<= 1) {
            int t = __shfl_up(x, d);
            if (lane >= d) x += t;
        }
        if (lane == 63) wsum[wid] = x;
        __syncthreads();
        if (wid == 0) {
            int y = (lane < 16) ? wsum[lane] : 0;
#pragma unroll
            for (int d = 1; d < 16; d <<= 1) {
                int t = __shfl_up(y, d);
                if (lane >= d) y += t;
            }
            if (lane < 16) wsum[lane] = y;
        }
        __syncthreads();
        int wbase = (wid > 0) ? wsum[wid - 1] : 0;
        int excl = s_carry + wbase + x - v;
        if (i < n) { offs[i] = excl; cursor[i] = excl; }
        __syncthreads();
        if (tid == 0) s_carry += wsum[15];
        __syncthreads();
    }
    if (threadIdx.x == 0) offs[n] = s_carry;
}

__global__ __launch_bounds__(256) void place_kernel(
    const int* __restrict__ e_card, const int* __restrict__ e_tx_c,
    const int* __restrict__ e_merch, const int* __restrict__ e_tx_m,
    int* __restrict__ cur_c, int* __restrict__ eidx_c,
    int* __restrict__ cur_m, int* __restrict__ eidx_m, int E)
{
    int i = blockIdx.x * 256 + threadIdx.x;
    if (i < E) {
        int pc = atomicAdd(&cur_c[e_card[i]], 1);
        eidx_c[pc] = e_tx_c[i];
        int pm = atomicAdd(&cur_m[e_merch[i]], 1);
        eidx_m[pm] = e_tx_m[i];
    }
}

// one wave per dst node: mean of gathered bf16 h rows (4B/lane, coalesced)
__global__ __launch_bounds__(256) void gather_mean(
    const unsigned short* __restrict__ h_src, const int* __restrict__ offs,
    const int* __restrict__ eidx, unsigned short* __restrict__ out_mean, int n_dst)
{
    const int lane = threadIdx.x & 63;
    const int d = blockIdx.x * 4 + (threadIdx.x >> 6);
    if (d >= n_dst) return;
    const int s = offs[d], e = offs[d + 1];
    float a0 = 0.f, a1 = 0.f;
    for (int p = s; p < e; ++p) {
        int tx = eidx[p];
        unsigned v = *reinterpret_cast<const unsigned*>(
            h_src + (size_t)tx * 128 + lane * 2);
        a0 += b2f((unsigned short)(v & 0xffff));
        a1 += b2f((unsigned short)(v >> 16));
    }
    const float inv = (e > s) ? 1.0f / (float)(e - s) : 0.f;
    unsigned o = ((unsigned)f2b(a1 * inv) << 16) | f2b(a0 * inv);
    *reinterpret_cast<unsigned*>(out_mean + (size_t)d * 128 + lane * 2) = o;
}

// ---------------------------------------------------------------------------
extern "C" void kernel_launch(void* const* d_in, const int* in_sizes, int n_in,
                              void* d_out, int out_size, void* d_ws, size_t ws_size,
                              hipStream_t stream)
{
    const float* tx_x        = (const float*)d_in[0];
    const int*   card_ids    = (const int*)d_in[1];
    const int*   merch_ids   = (const int*)d_in[2];
    const int*   e_card      = (const int*)d_in[3];
    const int*   e_tx_c      = (const int*)d_in[4];
    const int*   e_merch     = (const int*)d_in[5];
    const int*   e_tx_m      = (const int*)d_in[6];
    const float* card_emb    = (const float*)d_in[7];
    const float* merch_emb   = (const float*)d_in[8];
    const float* card_proj_W = (const float*)d_in[9];
    const float* card_proj_b = (const float*)d_in[10];
    const float* merch_proj_W= (const float*)d_in[11];
    const float* merch_proj_b= (const float*)d_in[12];
    const float* tx_W        = (const float*)d_in[13];
    const float* tx_b        = (const float*)d_in[14];
    const float* conv_Wl     = (const float*)d_in[15];
    const float* conv_bl     = (const float*)d_in[16];
    const float* conv_Wr     = (const float*)d_in[17];
    const float* h1_W        = (const float*)d_in[18];
    const float* h1_b        = (const float*)d_in[19];
    const float* h2_W        = (const float*)d_in[20];
    const float* h2_b        = (const float*)d_in[21];

    char* wsb = (char*)d_ws;
    auto alloc = [&](size_t bytes) {
        char* p = wsb; wsb += (bytes + 255) & ~(size_t)255; return p;
    };
    unsigned short* h_tx       = (unsigned short*)alloc((size_t)N_TX * 128 * 2);
    unsigned short* h_card     = (unsigned short*)alloc((size_t)N_CARD * 128 * 2);
    unsigned short* h_merch    = (unsigned short*)alloc((size_t)N_MERCH * 128 * 2);
    unsigned short* p_card     = (unsigned short*)alloc((size_t)N_CARD * 128 * 2);
    unsigned short* p_merch    = (unsigned short*)alloc((size_t)N_MERCH * 128 * 2);
    unsigned short* mean_card  = (unsigned short*)alloc((size_t)N_CARD * 128 * 2);
    unsigned short* mean_merch = (unsigned short*)alloc((size_t)N_MERCH * 128 * 2);
    unsigned short* WT         = (unsigned short*)alloc((size_t)18 * 16384 * 2);
    float* bsum = (float*)alloc(2 * 128 * 4);
    int* hist_c = (int*)alloc((size_t)(N_CARD + N_MERCH) * 4);  // one memset
    int* hist_m = hist_c + N_CARD;
    int* offs_c = (int*)alloc((size_t)(N_CARD + 1) * 4);
    int* cur_c  = (int*)alloc((size_t)N_CARD * 4);
    int* eidx_c = (int*)alloc((size_t)NE * 4);
    int* offs_m = (int*)alloc((size_t)(N_MERCH + 1) * 4);
    int* cur_m  = (int*)alloc((size_t)N_MERCH * 4);
    int* eidx_m = (int*)alloc((size_t)NE * 4);

    auto WTj = [&](int job) { return WT + (size_t)job * 16384; };

    auto gemm = [&](const void* A1, int a1f32, const int* ri, int K1,
                    const unsigned short* W1, const void* A2, int K2,
                    const unsigned short* W2, const float* bias,
                    const unsigned short* P1, const int* I1,
                    const unsigned short* P2, const int* I2, int relu,
                    const float* h2w, const float* h2bb, void* out, int M) {
        mfma_gemm<<<dim3((M + 127) / 128), dim3(256), 0, stream>>>(
            A1, a1f32, ri, K1, W1, A2, K2, W2, bias, P1, I1, P2, I2, relu,
            h2w, h2bb, out, M);
    };

    // weight prep + CSR build
    convert_weights<<<dim3(64, 18), dim3(256), 0, stream>>>(
        tx_W, card_proj_W, merch_proj_W, h1_W, conv_Wl, conv_Wr, conv_bl,
        WT, bsum);
    hipMemsetAsync(hist_c, 0, (size_t)(N_CARD + N_MERCH) * 4, stream);
    hist_kernel<<<dim3((NE + 255) / 256), dim3(256), 0, stream>>>(
        e_card, e_merch, hist_c, hist_m, NE);
    scan2_kernel<<<dim3(2), dim3(1024), 0, stream>>>(
        hist_c, offs_c, cur_c, N_CARD, hist_m, offs_m, cur_m, N_MERCH);
    place_kernel<<<dim3((NE + 255) / 256), dim3(256), 0, stream>>>(
        e_card, e_tx_c, e_merch, e_tx_m, cur_c, eidx_c, cur_m, eidx_m, NE);

    // input encoders (fp32 A converted inline during staging)
    gemm(tx_x, 1, nullptr, 128, WTj(0), nullptr, 0, nullptr, tx_b,
         nullptr, nullptr, nullptr, nullptr, 1, nullptr, nullptr, h_tx, N_TX);
    gemm(card_emb, 1, card_ids, 64, WTj(1), nullptr, 0, nullptr, card_proj_b,
         nullptr, nullptr, nullptr, nullptr, 0, nullptr, nullptr, h_card, N_CARD);
    gemm(merch_emb, 1, merch_ids, 64, WTj(2), nullptr, 0, nullptr, merch_proj_b,
         nullptr, nullptr, nullptr, nullptr, 0, nullptr, nullptr, h_merch, N_MERCH);

    for (int l = 0; l < 2; ++l) {
        const float* bl = conv_bl + (size_t)l * 4 * 128;
        int j = 4 + l * 7;   // Wl0,Wl1,Wl2,Wl3,Wr1,Wr3,Wsum

        gather_mean<<<dim3((N_CARD + 3) / 4), dim3(256), 0, stream>>>(
            h_tx, offs_c, eidx_c, mean_card, N_CARD);
        gather_mean<<<dim3((N_MERCH + 3) / 4), dim3(256), 0, stream>>>(
            h_tx, offs_m, eidx_m, mean_merch, N_MERCH);

        // p_* = h_* @ Wl[0/2] (pre-update hidden), for the tx-side gather
        gemm(h_card, 0, nullptr, 128, WTj(j + 0), nullptr, 0, nullptr, nullptr,
             nullptr, nullptr, nullptr, nullptr, 0, nullptr, nullptr, p_card, N_CARD);
        gemm(h_merch, 0, nullptr, 128, WTj(j + 2), nullptr, 0, nullptr, nullptr,
             nullptr, nullptr, nullptr, nullptr, 0, nullptr, nullptr, p_merch, N_MERCH);

        // card/merch updates: relu(mean@Wl + h@Wr + bl)  (in-place, row-local)
        gemm(mean_card, 0, nullptr, 128, WTj(j + 1), h_card, 128, WTj(j + 4),
             bl + 1 * 128, nullptr, nullptr, nullptr, nullptr, 1,
             nullptr, nullptr, h_card, N_CARD);
        gemm(mean_merch, 0, nullptr, 128, WTj(j + 3), h_merch, 128, WTj(j + 5),
             bl + 3 * 128, nullptr, nullptr, nullptr, nullptr, 1,
             nullptr, nullptr, h_merch, N_MERCH);

        // tx update: relu(h_tx@(Wr0+Wr2) + bl0+bl2 + p_card[e_card] + p_merch[e_merch])
        gemm(h_tx, 0, nullptr, 128, WTj(j + 6), nullptr, 0, nullptr,
             bsum + l * 128, p_card, e_card, p_merch, e_merch, 1,
             nullptr, nullptr, h_tx, N_TX);
    }

    // head: logits = relu(h_tx @ h1_W + h1_b) @ h2_W + h2_b  (fp32 out)
    gemm(h_tx, 0, nullptr, 128, WTj(3), nullptr, 0, nullptr, h1_b,
         nullptr, nullptr, nullptr, nullptr, 1, h2_W, h2_b, d_out, N_TX);
}